// Round 11
// baseline (390.118 us; speedup 1.0000x reference)
//
#include <hip/hip_runtime.h>

// SGCN fused, MFMA v8 = v7 with single-buffered g + __launch_bounds__(256,4).
// Goal: 4 blocks/CU (16 waves) within the measured 112-VGPR footprint (cap 128, no spill).
// out[n,f,t,w] = sum_c W[c,f]*g[c,w] + b[f]*s[w],  g[c,w] = sum_v x[n,c,t,v]*a[n,t,v,w]
// x[128,256,64,32] f32, a[128,64,32,32] f32, W[256,256] f32, b[256] f32
// d_out = out (67,108,864 f32) ++ a (8,388,608 f32);  d_ws = Wt f16 [f][c] (131072 B)

#define NN 128
#define CC 256
#define TT 64
#define VV 32
#define FF 256
#define TB 2
#define AL 33    // a_lds f32 row stride: ≡1 mod 32 -> ≤2-way on all accesses

typedef _Float16 half8 __attribute__((ext_vector_type(8)));
typedef _Float16 half4 __attribute__((ext_vector_type(4)));
typedef float floatx4 __attribute__((ext_vector_type(4)));

__global__ __launch_bounds__(256) void wt_prep_kernel(const float* __restrict__ W,
                                                      _Float16* __restrict__ Wt) {
    const int c = blockIdx.x;
    const int f = threadIdx.x;
    Wt[f * CC + c] = (_Float16)W[c * FF + f];
}

__global__ __launch_bounds__(256, 4) void sgcn_mfma8_kernel(
    const float* __restrict__ x, const float* __restrict__ a,
    const _Float16* __restrict__ Wt, const float* __restrict__ b,
    float* __restrict__ out, float* __restrict__ out_a)
{
    __shared__ float    a_lds[TB][VV][AL];      // 8448 B, f32 un-transposed
    __shared__ _Float16 g_lds[VV][256];         // 16 KB single buffer, row=512B, swizzled
    __shared__ float    s_lds[TB][VV];          // 256 B
    // total ~24.6 KB -> LDS allows 6 blocks; VGPR cap (256,4) -> 4 blocks/CU

    const int tid  = threadIdx.x;
    const int lane = tid & 63;
    const int wv   = tid >> 6;       // wave 0..3
    const int l15  = lane & 15;
    const int lg   = lane >> 4;      // 0..3
    const int blk  = blockIdx.x;
    const int n    = blk >> 5;       // TT/TB = 32 t-groups per n
    const int t0   = (blk & 31) * TB;

    // ---- Wt fragment loads (compiler sinks these to L2 hits inside GEMM-B; fine)
    half8 wb[32];
    #pragma unroll
    for (int fi = 0; fi < 4; ++fi) {
        const int f = 16 * (wv * 4 + fi) + l15;
        const _Float16* wp = Wt + (size_t)f * CC + 8 * lg;
        #pragma unroll
        for (int ks = 0; ks < 8; ++ks)
            wb[fi * 8 + ks] = *reinterpret_cast<const half8*>(wp + 32 * ks);
    }

    // ---- x prefetch for it=0 (in flight under a-staging + barrier)
    float4 xf[8];
    #pragma unroll
    for (int ci = 0; ci < 4; ++ci) {
        const int c = (wv * 4 + ci) * 16 + l15;
        const float* xp = x + (((size_t)n * CC + c) * TT + t0) * VV + 8 * lg;
        xf[ci * 2 + 0] = *reinterpret_cast<const float4*>(xp);
        xf[ci * 2 + 1] = *reinterpret_cast<const float4*>(xp + 4);
    }

    // ---- phase 0: load a (TB t's), mirror to out tail, stage f32 into LDS
    {
        const int v  = tid >> 3;
        const int w0 = (tid & 7) * 4;
        #pragma unroll
        for (int it = 0; it < TB; ++it) {
            const size_t off = ((size_t)(n * TT + t0 + it)) * (VV * VV) + tid * 4;
            float4 av = *reinterpret_cast<const float4*>(a + off);
            *reinterpret_cast<float4*>(out_a + off) = av;
            a_lds[it][v][w0 + 0] = av.x;
            a_lds[it][v][w0 + 1] = av.y;
            a_lds[it][v][w0 + 2] = av.z;
            a_lds[it][v][w0 + 3] = av.w;
        }
    }

    float bv[4];
    #pragma unroll
    for (int fi = 0; fi < 4; ++fi) bv[fi] = b[16 * (wv * 4 + fi) + l15];

    __syncthreads();                  // a_lds ready

    // ---- column sums s[it][w] (consumed after the it=0 g-barrier)
    if (tid < TB * VV) {
        const int it = tid >> 5, w = tid & 31;
        float ss = 0.0f;
        #pragma unroll
        for (int v = 0; v < VV; ++v) ss += a_lds[it][v][w];
        s_lds[it][w] = ss;
    }

    char* gbase = (char*)&g_lds[0][0];

    #pragma unroll
    for (int it = 0; it < TB; ++it) {
        // ---- convert prefetched x -> A-frags (frees xf for next prefetch)
        half8 af[4];
        #pragma unroll
        for (int ci = 0; ci < 4; ++ci) {
            float4 x0 = xf[ci * 2 + 0], x1 = xf[ci * 2 + 1];
            af[ci][0] = (_Float16)x0.x; af[ci][1] = (_Float16)x0.y;
            af[ci][2] = (_Float16)x0.z; af[ci][3] = (_Float16)x0.w;
            af[ci][4] = (_Float16)x1.x; af[ci][5] = (_Float16)x1.y;
            af[ci][6] = (_Float16)x1.z; af[ci][7] = (_Float16)x1.w;
        }

        // ---- cross-it prefetch: x for it+1 (in flight across GEMM-A+barriers+GEMM-B)
        if (it + 1 < TB) {
            #pragma unroll
            for (int ci = 0; ci < 4; ++ci) {
                const int c = (wv * 4 + ci) * 16 + l15;
                const float* xp = x + (((size_t)n * CC + c) * TT + (t0 + it + 1)) * VV + 8 * lg;
                xf[ci * 2 + 0] = *reinterpret_cast<const float4*>(xp);
                xf[ci * 2 + 1] = *reinterpret_cast<const float4*>(xp + 4);
            }
        }

        // ---- B-frags of a: col w=16wt+l15, k=v=8lg+j (scalar LDS reads, <=2-way)
        half8 bA0, bA1;
        #pragma unroll
        for (int j = 0; j < 8; ++j) {
            bA0[j] = (_Float16)a_lds[it][8 * lg + j][l15];
            bA1[j] = (_Float16)a_lds[it][8 * lg + j][16 + l15];
        }

        // ---- GEMM-A: g[c,w]; write g^T rows with XOR swizzle (byte ^= (row&7)<<4)
        #pragma unroll
        for (int ci = 0; ci < 4; ++ci) {
            const int ct = wv * 4 + ci;
            #pragma unroll
            for (int wt = 0; wt < 2; ++wt) {
                floatx4 acc = {0.f, 0.f, 0.f, 0.f};
                acc = __builtin_amdgcn_mfma_f32_16x16x32_f16(af[ci], wt ? bA1 : bA0, acc, 0, 0, 0);
                half4 gh;
                gh[0] = (_Float16)acc[0]; gh[1] = (_Float16)acc[1];
                gh[2] = (_Float16)acc[2]; gh[3] = (_Float16)acc[3];
                const int row = 16 * wt + l15;
                const int col_b = (ct * 16 + 4 * lg) * 2;            // 8B-aligned
                *reinterpret_cast<half4*>(gbase + row * 512 +
                                          (col_b ^ ((row & 7) << 4))) = gh;
            }
        }
        __syncthreads();              // g ready (it=0: also s_lds ready)

        // ---- GEMM-B: D[w,f] = g^T · Wt
        floatx4 acc2[8];
        #pragma unroll
        for (int q = 0; q < 8; ++q) acc2[q] = (floatx4){0.f, 0.f, 0.f, 0.f};

        __builtin_amdgcn_s_setprio(1);
        #pragma unroll
        for (int ks = 0; ks < 8; ++ks) {
            const int r0 = l15, r1 = 16 + l15;
            const int cb = (32 * ks + 8 * lg) * 2;                   // 16B-aligned
            half8 ga0 = *reinterpret_cast<const half8*>(gbase + r0 * 512 +
                                                        (cb ^ ((r0 & 7) << 4)));
            half8 ga1 = *reinterpret_cast<const half8*>(gbase + r1 * 512 +
                                                        (cb ^ ((r1 & 7) << 4)));
            #pragma unroll
            for (int fi = 0; fi < 4; ++fi) {
                acc2[fi * 2 + 0] = __builtin_amdgcn_mfma_f32_16x16x32_f16(ga0, wb[fi * 8 + ks], acc2[fi * 2 + 0], 0, 0, 0);
                acc2[fi * 2 + 1] = __builtin_amdgcn_mfma_f32_16x16x32_f16(ga1, wb[fi * 8 + ks], acc2[fi * 2 + 1], 0, 0, 0);
            }
        }
        __builtin_amdgcn_s_setprio(0);

        // ---- epilogue: out[n,f,t,w0..3] = acc + b[f]*s[w]  (float4 stores)
        #pragma unroll
        for (int fi = 0; fi < 4; ++fi) {
            const int f = 16 * (wv * 4 + fi) + l15;
            float* ob = out + (((size_t)n * FF + f) * TT + (t0 + it)) * VV;
            #pragma unroll
            for (int mt = 0; mt < 2; ++mt) {
                const int w0 = 16 * mt + 4 * lg;
                float4 sv = *reinterpret_cast<const float4*>(&s_lds[it][w0]);
                float4 o;
                o.x = acc2[fi * 2 + mt][0] + bv[fi] * sv.x;
                o.y = acc2[fi * 2 + mt][1] + bv[fi] * sv.y;
                o.z = acc2[fi * 2 + mt][2] + bv[fi] * sv.z;
                o.w = acc2[fi * 2 + mt][3] + bv[fi] * sv.w;
                *reinterpret_cast<float4*>(ob + w0) = o;
            }
        }
        if (it + 1 < TB) __syncthreads();   // single g buffer: reads done before overwrite
    }
}

// ---- fallback (verified round-3 scalar kernel): used only if ws too small
__global__ __launch_bounds__(256) void sgcn_fused_kernel(
    const float* __restrict__ x, const float* __restrict__ a,
    const float* __restrict__ W, const float* __restrict__ b,
    float* __restrict__ out, float* __restrict__ out_a)
{
    __shared__ float x_lds[CC][VV];
    __shared__ float a_lds[VV][VV];
    const int tid = threadIdx.x;
    const int nt  = blockIdx.x;
    const int n   = nt >> 6;
    const int t   = nt & 63;
    const float* xb = x + (size_t)n * CC * TT * VV + (size_t)t * VV;
    #pragma unroll
    for (int k = 0; k < 8; ++k) {
        int e = tid * 4 + k * 1024;
        int c = e >> 5, v = e & 31;
        float4 val = *reinterpret_cast<const float4*>(xb + (size_t)c * (TT * VV) + v);
        *reinterpret_cast<float4*>(&x_lds[c][v]) = val;
    }
    {
        const float* ab = a + (size_t)nt * (VV * VV);
        float4 av = *reinterpret_cast<const float4*>(ab + tid * 4);
        *reinterpret_cast<float4*>(&a_lds[0][0] + tid * 4) = av;
        *reinterpret_cast<float4*>(out_a + (size_t)nt * (VV * VV) + tid * 4) = av;
    }
    __syncthreads();
    const int f = tid;
    float h[VV];
    #pragma unroll
    for (int v = 0; v < VV; ++v) h[v] = 0.0f;
    #pragma unroll 4
    for (int c = 0; c < CC; ++c) {
        float wv = W[c * FF + f];
        #pragma unroll
        for (int v = 0; v < VV; ++v) h[v] = fmaf(x_lds[c][v], wv, h[v]);
    }
    const float bias = b[f];
    #pragma unroll
    for (int v = 0; v < VV; ++v) h[v] += bias;
    float o[VV];
    #pragma unroll
    for (int w = 0; w < VV; ++w) o[w] = 0.0f;
    #pragma unroll
    for (int v = 0; v < VV; ++v) {
        float hv = h[v];
        #pragma unroll
        for (int w = 0; w < VV; ++w) o[w] = fmaf(hv, a_lds[v][w], o[w]);
    }
    float* ob = out + (((size_t)n * FF + f) * TT + t) * VV;
    #pragma unroll
    for (int w = 0; w < VV; w += 4)
        *reinterpret_cast<float4*>(ob + w) = make_float4(o[w], o[w+1], o[w+2], o[w+3]);
}

extern "C" void kernel_launch(void* const* d_in, const int* in_sizes, int n_in,
                              void* d_out, int out_size, void* d_ws, size_t ws_size,
                              hipStream_t stream) {
    const float* x = (const float*)d_in[0];
    const float* a = (const float*)d_in[1];
    const float* W = (const float*)d_in[2];
    const float* b = (const float*)d_in[3];

    float* out   = (float*)d_out;
    float* out_a = out + (size_t)NN * FF * TT * VV;

    const size_t wt_bytes = (size_t)FF * CC * sizeof(_Float16);  // 131072

    if (ws_size >= wt_bytes) {
        _Float16* Wt = (_Float16*)d_ws;
        wt_prep_kernel<<<dim3(CC), dim3(FF), 0, stream>>>(W, Wt);
        sgcn_mfma8_kernel<<<dim3(NN * (TT / TB)), dim3(256), 0, stream>>>(x, a, Wt, b, out, out_a);
    } else {
        sgcn_fused_kernel<<<dim3(NN * TT), dim3(256), 0, stream>>>(x, a, W, b, out, out_a);
    }
}

// Round 12
// 157.123 us; speedup vs baseline: 2.4829x; 2.4829x over previous
//
#include <hip/hip_runtime.h>

// SGCN fused, MFMA v9: 512-thread blocks (8 waves), wave owns 2 f-tiles ->
// wb[16] (64 VGPR) genuinely register-resident under bounds(512,2); GEMM-B is
// pure LDS+MFMA. 2 blocks/CU = 16 waves/CU. Single g buffer, r6 swizzles.
// out[n,f,t,w] = sum_c W[c,f]*g[c,w] + b[f]*s[w],  g[c,w] = sum_v x[n,c,t,v]*a[n,t,v,w]
// x[128,256,64,32] f32, a[128,64,32,32] f32, W[256,256] f32, b[256] f32
// d_out = out (67,108,864 f32) ++ a (8,388,608 f32);  d_ws = Wt f16 [f][c] (131072 B)

#define NN 128
#define CC 256
#define TT 64
#define VV 32
#define FF 256
#define TB 2
#define AL 33    // a_lds f32 row stride: ≡1 mod 32 -> ≤2-way on all accesses

typedef _Float16 half8 __attribute__((ext_vector_type(8)));
typedef _Float16 half4 __attribute__((ext_vector_type(4)));
typedef float floatx4 __attribute__((ext_vector_type(4)));

__global__ __launch_bounds__(256) void wt_prep_kernel(const float* __restrict__ W,
                                                      _Float16* __restrict__ Wt) {
    const int c = blockIdx.x;
    const int f = threadIdx.x;
    Wt[f * CC + c] = (_Float16)W[c * FF + f];
}

__global__ __launch_bounds__(512, 2) void sgcn_mfma9_kernel(
    const float* __restrict__ x, const float* __restrict__ a,
    const _Float16* __restrict__ Wt, const float* __restrict__ b,
    float* __restrict__ out, float* __restrict__ out_a)
{
    __shared__ float    a_lds[TB][VV][AL];      // 8448 B, f32 un-transposed
    __shared__ _Float16 g_lds[VV][256];         // 16 KB single buffer, row=512B, swizzled
    __shared__ float    s_lds[TB][VV];          // 256 B
    // total ~24.6 KB -> LDS allows 6 blocks; VGPR cap (512,2)=128 -> 2 blocks/CU

    const int tid  = threadIdx.x;
    const int lane = tid & 63;
    const int wv   = tid >> 6;       // wave 0..7
    const int l15  = lane & 15;
    const int lg   = lane >> 4;      // 0..3
    const int blk  = blockIdx.x;
    const int n    = blk >> 5;       // TT/TB = 32 t-groups per n
    const int t0   = (blk & 31) * TB;

    // ---- Wt hoist: 2 f-tiles per wave -> wb[16] = 64 VGPR (fits under the cap).
    // Issued first so L2 latency hides under a-staging + barrier.
    half8 wb[16];
    #pragma unroll
    for (int fi = 0; fi < 2; ++fi) {
        const int f = 16 * (wv * 2 + fi) + l15;
        const _Float16* wp = Wt + (size_t)f * CC + 8 * lg;
        #pragma unroll
        for (int ks = 0; ks < 8; ++ks)
            wb[fi * 8 + ks] = *reinterpret_cast<const half8*>(wp + 32 * ks);
    }

    // ---- phase 0: load a (TB t's) with one float4 per thread, mirror, stage f32
    {
        const int e  = tid * 4;           // [0, 2048) = TB*1024
        const int it = e >> 10;
        const int r  = e & 1023;
        const int v  = r >> 5;
        const int w0 = r & 31;
        const size_t off = ((size_t)(n * TT + t0 + it)) * (VV * VV) + r;
        float4 av = *reinterpret_cast<const float4*>(a + off);
        *reinterpret_cast<float4*>(out_a + off) = av;
        a_lds[it][v][w0 + 0] = av.x;
        a_lds[it][v][w0 + 1] = av.y;
        a_lds[it][v][w0 + 2] = av.z;
        a_lds[it][v][w0 + 3] = av.w;
    }

    float bv[2];
    #pragma unroll
    for (int fi = 0; fi < 2; ++fi) bv[fi] = b[16 * (wv * 2 + fi) + l15];

    __syncthreads();                  // a_lds ready

    // ---- column sums s[it][w] (consumed after the it=0 g-barrier)
    if (tid < TB * VV) {
        const int it = tid >> 5, w = tid & 31;
        float ss = 0.0f;
        #pragma unroll
        for (int v = 0; v < VV; ++v) ss += a_lds[it][v][w];
        s_lds[it][w] = ss;
    }

    char* gbase = (char*)&g_lds[0][0];

    #pragma unroll
    for (int it = 0; it < TB; ++it) {
        // ---- x loads: this wave's 2 c-tiles (4 b128, batched in flight)
        float4 xf[4];
        #pragma unroll
        for (int ci = 0; ci < 2; ++ci) {
            const int c = (wv * 2 + ci) * 16 + l15;
            const float* xp = x + (((size_t)n * CC + c) * TT + (t0 + it)) * VV + 8 * lg;
            xf[ci * 2 + 0] = *reinterpret_cast<const float4*>(xp);
            xf[ci * 2 + 1] = *reinterpret_cast<const float4*>(xp + 4);
        }

        // ---- B-frags of a: col w=16wt+l15, k=v=8lg+j (scalar LDS reads, <=2-way)
        half8 bA0, bA1;
        #pragma unroll
        for (int j = 0; j < 8; ++j) {
            bA0[j] = (_Float16)a_lds[it][8 * lg + j][l15];
            bA1[j] = (_Float16)a_lds[it][8 * lg + j][16 + l15];
        }

        // ---- A-frags from x
        half8 af[2];
        #pragma unroll
        for (int ci = 0; ci < 2; ++ci) {
            float4 x0 = xf[ci * 2 + 0], x1 = xf[ci * 2 + 1];
            af[ci][0] = (_Float16)x0.x; af[ci][1] = (_Float16)x0.y;
            af[ci][2] = (_Float16)x0.z; af[ci][3] = (_Float16)x0.w;
            af[ci][4] = (_Float16)x1.x; af[ci][5] = (_Float16)x1.y;
            af[ci][6] = (_Float16)x1.z; af[ci][7] = (_Float16)x1.w;
        }

        // ---- GEMM-A: g[c,w] for 2 c-tiles; write g^T rows, XOR swizzle
        #pragma unroll
        for (int ci = 0; ci < 2; ++ci) {
            const int ct = wv * 2 + ci;
            #pragma unroll
            for (int wt = 0; wt < 2; ++wt) {
                floatx4 acc = {0.f, 0.f, 0.f, 0.f};
                acc = __builtin_amdgcn_mfma_f32_16x16x32_f16(af[ci], wt ? bA1 : bA0, acc, 0, 0, 0);
                half4 gh;
                gh[0] = (_Float16)acc[0]; gh[1] = (_Float16)acc[1];
                gh[2] = (_Float16)acc[2]; gh[3] = (_Float16)acc[3];
                const int row = 16 * wt + l15;
                const int col_b = (ct * 16 + 4 * lg) * 2;            // 8B-aligned
                *reinterpret_cast<half4*>(gbase + row * 512 +
                                          (col_b ^ ((row & 7) << 4))) = gh;
            }
        }
        __syncthreads();              // g ready (it=0: also s_lds ready)

        // ---- GEMM-B: D[w,f] = g^T · Wt, Wt from registers (pure LDS+MFMA)
        floatx4 acc2[4];              // [fi][mt]
        #pragma unroll
        for (int q = 0; q < 4; ++q) acc2[q] = (floatx4){0.f, 0.f, 0.f, 0.f};

        __builtin_amdgcn_s_setprio(1);
        #pragma unroll
        for (int ks = 0; ks < 8; ++ks) {
            const int r0 = l15, r1 = 16 + l15;
            const int cb = (32 * ks + 8 * lg) * 2;                   // 16B-aligned
            half8 ga0 = *reinterpret_cast<const half8*>(gbase + r0 * 512 +
                                                        (cb ^ ((r0 & 7) << 4)));
            half8 ga1 = *reinterpret_cast<const half8*>(gbase + r1 * 512 +
                                                        (cb ^ ((r1 & 7) << 4)));
            #pragma unroll
            for (int fi = 0; fi < 2; ++fi) {
                acc2[fi * 2 + 0] = __builtin_amdgcn_mfma_f32_16x16x32_f16(ga0, wb[fi * 8 + ks], acc2[fi * 2 + 0], 0, 0, 0);
                acc2[fi * 2 + 1] = __builtin_amdgcn_mfma_f32_16x16x32_f16(ga1, wb[fi * 8 + ks], acc2[fi * 2 + 1], 0, 0, 0);
            }
        }
        __builtin_amdgcn_s_setprio(0);

        // ---- epilogue: out[n,f,t,w0..3] = acc + b[f]*s[w]  (float4 stores)
        #pragma unroll
        for (int fi = 0; fi < 2; ++fi) {
            const int f = 16 * (wv * 2 + fi) + l15;
            float* ob = out + (((size_t)n * FF + f) * TT + (t0 + it)) * VV;
            #pragma unroll
            for (int mt = 0; mt < 2; ++mt) {
                const int w0 = 16 * mt + 4 * lg;
                float4 sv = *reinterpret_cast<const float4*>(&s_lds[it][w0]);
                float4 o;
                o.x = acc2[fi * 2 + mt][0] + bv[fi] * sv.x;
                o.y = acc2[fi * 2 + mt][1] + bv[fi] * sv.y;
                o.z = acc2[fi * 2 + mt][2] + bv[fi] * sv.z;
                o.w = acc2[fi * 2 + mt][3] + bv[fi] * sv.w;
                *reinterpret_cast<float4*>(ob + w0) = o;
            }
        }
        if (it + 1 < TB) __syncthreads();   // single g buffer: reads done before overwrite
    }
}

// ---- fallback (verified round-3 scalar kernel): used only if ws too small
__global__ __launch_bounds__(256) void sgcn_fused_kernel(
    const float* __restrict__ x, const float* __restrict__ a,
    const float* __restrict__ W, const float* __restrict__ b,
    float* __restrict__ out, float* __restrict__ out_a)
{
    __shared__ float x_lds[CC][VV];
    __shared__ float a_lds[VV][VV];
    const int tid = threadIdx.x;
    const int nt  = blockIdx.x;
    const int n   = nt >> 6;
    const int t   = nt & 63;
    const float* xb = x + (size_t)n * CC * TT * VV + (size_t)t * VV;
    #pragma unroll
    for (int k = 0; k < 8; ++k) {
        int e = tid * 4 + k * 1024;
        int c = e >> 5, v = e & 31;
        float4 val = *reinterpret_cast<const float4*>(xb + (size_t)c * (TT * VV) + v);
        *reinterpret_cast<float4*>(&x_lds[c][v]) = val;
    }
    {
        const float* ab = a + (size_t)nt * (VV * VV);
        float4 av = *reinterpret_cast<const float4*>(ab + tid * 4);
        *reinterpret_cast<float4*>(&a_lds[0][0] + tid * 4) = av;
        *reinterpret_cast<float4*>(out_a + (size_t)nt * (VV * VV) + tid * 4) = av;
    }
    __syncthreads();
    const int f = tid;
    float h[VV];
    #pragma unroll
    for (int v = 0; v < VV; ++v) h[v] = 0.0f;
    #pragma unroll 4
    for (int c = 0; c < CC; ++c) {
        float wv = W[c * FF + f];
        #pragma unroll
        for (int v = 0; v < VV; ++v) h[v] = fmaf(x_lds[c][v], wv, h[v]);
    }
    const float bias = b[f];
    #pragma unroll
    for (int v = 0; v < VV; ++v) h[v] += bias;
    float o[VV];
    #pragma unroll
    for (int w = 0; w < VV; ++w) o[w] = 0.0f;
    #pragma unroll
    for (int v = 0; v < VV; ++v) {
        float hv = h[v];
        #pragma unroll
        for (int w = 0; w < VV; ++w) o[w] = fmaf(hv, a_lds[v][w], o[w]);
    }
    float* ob = out + (((size_t)n * FF + f) * TT + t) * VV;
    #pragma unroll
    for (int w = 0; w < VV; w += 4)
        *reinterpret_cast<float4*>(ob + w) = make_float4(o[w], o[w+1], o[w+2], o[w+3]);
}

extern "C" void kernel_launch(void* const* d_in, const int* in_sizes, int n_in,
                              void* d_out, int out_size, void* d_ws, size_t ws_size,
                              hipStream_t stream) {
    const float* x = (const float*)d_in[0];
    const float* a = (const float*)d_in[1];
    const float* W = (const float*)d_in[2];
    const float* b = (const float*)d_in[3];

    float* out   = (float*)d_out;
    float* out_a = out + (size_t)NN * FF * TT * VV;

    const size_t wt_bytes = (size_t)FF * CC * sizeof(_Float16);  // 131072

    if (ws_size >= wt_bytes) {
        _Float16* Wt = (_Float16*)d_ws;
        wt_prep_kernel<<<dim3(CC), dim3(FF), 0, stream>>>(W, Wt);
        sgcn_mfma9_kernel<<<dim3(NN * (TT / TB)), dim3(512), 0, stream>>>(x, a, Wt, b, out, out_a);
    } else {
        sgcn_fused_kernel<<<dim3(NN * TT), dim3(256), 0, stream>>>(x, a, W, b, out, out_a);
    }
}

// Round 13
// 145.692 us; speedup vs baseline: 2.6777x; 1.0785x over previous
//
#include <hip/hip_runtime.h>

// SGCN fused, MFMA v10: 512 threads, TB=4, two barriers per block.
// Phase1: GEMM-A for all 4 t (2 waves/t, 8 c-tiles each, batched x loads).
// Phase2: GEMM-B, wave owns f-tiles {wv, wv+8}; wb[8] loaded once per f-tile,
// reused across 4 t; 128 MFMA/wave, no barriers, no HBM loads.
// out[n,f,t,w] = sum_c W[c,f]*g[c,w] + b[f]*s[w],  g[c,w] = sum_v x[n,c,t,v]*a[n,t,v,w]
// d_out = out (67,108,864 f32) ++ a (8,388,608 f32);  d_ws = Wt f16 [f][c] (131072 B)

#define NN 128
#define CC 256
#define TT 64
#define VV 32
#define FF 256
#define TB 4

typedef _Float16 half8 __attribute__((ext_vector_type(8)));
typedef _Float16 half4 __attribute__((ext_vector_type(4)));
typedef float floatx4 __attribute__((ext_vector_type(4)));

__global__ __launch_bounds__(256) void wt_prep_kernel(const float* __restrict__ W,
                                                      _Float16* __restrict__ Wt) {
    const int c = blockIdx.x;
    const int f = threadIdx.x;
    Wt[f * CC + c] = (_Float16)W[c * FF + f];
}

__global__ __launch_bounds__(512, 2) void sgcn_mfma10_kernel(
    const float* __restrict__ x, const float* __restrict__ a,
    const _Float16* __restrict__ Wt, const float* __restrict__ b,
    float* __restrict__ out, float* __restrict__ out_a)
{
    // a_t: rows (it*32+w), 32 f16 v's, 64B/row, swizzle byte ^= (row&3)<<4  (v4-verified)
    __shared__ _Float16 a_t[TB * VV * VV];       // 8 KB
    // g: per-t [32 w-rows][256 c] f16, 512B/row, swizzle byte ^= (row&7)<<4 (r6-verified)
    __shared__ _Float16 g_s[TB * VV * 256];      // 64 KB
    __shared__ float    s_lds[TB][VV];           // 512 B
    // total 72.7 KB -> 2 blocks/CU; bounds(512,2) caps VGPR at 128

    const int tid  = threadIdx.x;
    const int lane = tid & 63;
    const int wv   = tid >> 6;       // wave 0..7
    const int l15  = lane & 15;
    const int lg   = lane >> 4;      // 0..3
    const int blk  = blockIdx.x;
    const int n    = blk >> 4;       // TT/TB = 16 t-groups per n
    const int t0   = (blk & 15) * TB;

    char* at_base = (char*)a_t;
    char* g_base  = (char*)g_s;

    const int tA    = wv >> 1;       // phase-1: this wave's t (0..3)
    const int chalf = wv & 1;        // phase-1: c-tile half (0..7 or 8..15)

    // ---- phase-1 x loads issued FIRST: 16 b128 in flight under all of a-staging
    float4 xf[16];
    #pragma unroll
    for (int ci = 0; ci < 8; ++ci) {
        const int c = (chalf * 8 + ci) * 16 + l15;
        const float* xp = x + (((size_t)n * CC + c) * TT + (t0 + tA)) * VV + 8 * lg;
        xf[ci * 2 + 0] = *reinterpret_cast<const float4*>(xp);
        xf[ci * 2 + 1] = *reinterpret_cast<const float4*>(xp + 4);
    }

    // ---- phase 0: stage a (4 t's): 2 float4 per thread, mirror, transposed f16 a_t
    #pragma unroll
    for (int k = 0; k < 2; ++k) {
        const int o  = (tid + 512 * k) * 4;      // flat f32 offset in [0, 4096)
        const int it = o >> 10;
        const int r  = o & 1023;                 // v*32 + w
        const int v  = r >> 5;
        const int w0 = r & 31;
        const size_t off = ((size_t)(n * TT + t0 + it)) * (VV * VV) + r;
        float4 av = *reinterpret_cast<const float4*>(a + off);
        *reinterpret_cast<float4*>(out_a + off) = av;
        #pragma unroll
        for (int j = 0; j < 4; ++j) {
            const int row = it * VV + w0 + j;
            const float e = j == 0 ? av.x : j == 1 ? av.y : j == 2 ? av.z : av.w;
            *reinterpret_cast<_Float16*>(at_base + row * 64 +
                                         ((v * 2) ^ ((row & 3) << 4))) = (_Float16)e;
        }
    }

    __syncthreads();                 // a_t ready

    // ---- s[it][w] from a_t (tid<128; written before barrier 2, read after it)
    if (tid < TB * VV) {
        const int it = tid >> 5, w = tid & 31;
        const int row = it * VV + w;
        float ss = 0.0f;
        #pragma unroll
        for (int v = 0; v < VV; ++v)
            ss += (float)*reinterpret_cast<const _Float16*>(
                at_base + row * 64 + ((v * 2) ^ ((row & 3) << 4)));
        s_lds[it][w] = ss;
    }

    // ---- phase 1: GEMM-A for own t, 8 c-tiles; write swizzled g[tA]
    {
        const int r0 = tA * VV + l15, r1 = r0 + 16;
        half8 bA0 = *reinterpret_cast<const half8*>(at_base + r0 * 64 +
                                                    ((16 * lg) ^ ((r0 & 3) << 4)));
        half8 bA1 = *reinterpret_cast<const half8*>(at_base + r1 * 64 +
                                                    ((16 * lg) ^ ((r1 & 3) << 4)));
        char* gt = g_base + tA * (VV * 256 * 2);
        #pragma unroll
        for (int ci = 0; ci < 8; ++ci) {
            const int ct = chalf * 8 + ci;
            half8 af;
            float4 x0 = xf[ci * 2 + 0], x1 = xf[ci * 2 + 1];
            af[0] = (_Float16)x0.x; af[1] = (_Float16)x0.y;
            af[2] = (_Float16)x0.z; af[3] = (_Float16)x0.w;
            af[4] = (_Float16)x1.x; af[5] = (_Float16)x1.y;
            af[6] = (_Float16)x1.z; af[7] = (_Float16)x1.w;
            #pragma unroll
            for (int wt = 0; wt < 2; ++wt) {
                floatx4 acc = {0.f, 0.f, 0.f, 0.f};
                acc = __builtin_amdgcn_mfma_f32_16x16x32_f16(af, wt ? bA1 : bA0, acc, 0, 0, 0);
                half4 gh;
                gh[0] = (_Float16)acc[0]; gh[1] = (_Float16)acc[1];
                gh[2] = (_Float16)acc[2]; gh[3] = (_Float16)acc[3];
                const int row = 16 * wt + l15;
                const int cb  = (ct * 16 + 4 * lg) * 2;
                *reinterpret_cast<half4*>(gt + row * 512 + (cb ^ ((row & 7) << 4))) = gh;
            }
        }
    }
    __syncthreads();                 // g (all 4 t) + s_lds ready

    // ---- phase 2: GEMM-B. Wave owns f-tiles {wv, wv+8}; wb reused across 4 t.
    #pragma unroll
    for (int fth = 0; fth < 2; ++fth) {
        const int ft = fth * 8 + wv;
        const int f  = ft * 16 + l15;
        half8 wb[8];
        const _Float16* wp = Wt + (size_t)f * CC + 8 * lg;
        #pragma unroll
        for (int ks = 0; ks < 8; ++ks)
            wb[ks] = *reinterpret_cast<const half8*>(wp + 32 * ks);
        const float bvf = b[f];

        #pragma unroll
        for (int tt = 0; tt < TB; ++tt) {
            char* gt = g_base + tt * (VV * 256 * 2);
            floatx4 acc2[2];
            acc2[0] = (floatx4){0.f, 0.f, 0.f, 0.f};
            acc2[1] = (floatx4){0.f, 0.f, 0.f, 0.f};

            __builtin_amdgcn_s_setprio(1);
            #pragma unroll
            for (int ks = 0; ks < 8; ++ks) {
                const int r0 = l15, r1 = 16 + l15;
                const int cb = (32 * ks + 8 * lg) * 2;
                half8 ga0 = *reinterpret_cast<const half8*>(gt + r0 * 512 +
                                                            (cb ^ ((r0 & 7) << 4)));
                half8 ga1 = *reinterpret_cast<const half8*>(gt + r1 * 512 +
                                                            (cb ^ ((r1 & 7) << 4)));
                acc2[0] = __builtin_amdgcn_mfma_f32_16x16x32_f16(ga0, wb[ks], acc2[0], 0, 0, 0);
                acc2[1] = __builtin_amdgcn_mfma_f32_16x16x32_f16(ga1, wb[ks], acc2[1], 0, 0, 0);
            }
            __builtin_amdgcn_s_setprio(0);

            float* ob = out + (((size_t)n * FF + f) * TT + (t0 + tt)) * VV;
            #pragma unroll
            for (int mt = 0; mt < 2; ++mt) {
                const int w0 = 16 * mt + 4 * lg;
                float4 sv = *reinterpret_cast<const float4*>(&s_lds[tt][w0]);
                float4 o;
                o.x = acc2[mt][0] + bvf * sv.x;
                o.y = acc2[mt][1] + bvf * sv.y;
                o.z = acc2[mt][2] + bvf * sv.z;
                o.w = acc2[mt][3] + bvf * sv.w;
                *reinterpret_cast<float4*>(ob + w0) = o;
            }
        }
    }
}

// ---- fallback (verified round-3 scalar kernel): used only if ws too small
__global__ __launch_bounds__(256) void sgcn_fused_kernel(
    const float* __restrict__ x, const float* __restrict__ a,
    const float* __restrict__ W, const float* __restrict__ b,
    float* __restrict__ out, float* __restrict__ out_a)
{
    __shared__ float x_lds[CC][VV];
    __shared__ float a_lds[VV][VV];
    const int tid = threadIdx.x;
    const int nt  = blockIdx.x;
    const int n   = nt >> 6;
    const int t   = nt & 63;
    const float* xb = x + (size_t)n * CC * TT * VV + (size_t)t * VV;
    #pragma unroll
    for (int k = 0; k < 8; ++k) {
        int e = tid * 4 + k * 1024;
        int c = e >> 5, v = e & 31;
        float4 val = *reinterpret_cast<const float4*>(xb + (size_t)c * (TT * VV) + v);
        *reinterpret_cast<float4*>(&x_lds[c][v]) = val;
    }
    {
        const float* ab = a + (size_t)nt * (VV * VV);
        float4 av = *reinterpret_cast<const float4*>(ab + tid * 4);
        *reinterpret_cast<float4*>(&a_lds[0][0] + tid * 4) = av;
        *reinterpret_cast<float4*>(out_a + (size_t)nt * (VV * VV) + tid * 4) = av;
    }
    __syncthreads();
    const int f = tid;
    float h[VV];
    #pragma unroll
    for (int v = 0; v < VV; ++v) h[v] = 0.0f;
    #pragma unroll 4
    for (int c = 0; c < CC; ++c) {
        float wv = W[c * FF + f];
        #pragma unroll
        for (int v = 0; v < VV; ++v) h[v] = fmaf(x_lds[c][v], wv, h[v]);
    }
    const float bias = b[f];
    #pragma unroll
    for (int v = 0; v < VV; ++v) h[v] += bias;
    float o[VV];
    #pragma unroll
    for (int w = 0; w < VV; ++w) o[w] = 0.0f;
    #pragma unroll
    for (int v = 0; v < VV; ++v) {
        float hv = h[v];
        #pragma unroll
        for (int w = 0; w < VV; ++w) o[w] = fmaf(hv, a_lds[v][w], o[w]);
    }
    float* ob = out + (((size_t)n * FF + f) * TT + t) * VV;
    #pragma unroll
    for (int w = 0; w < VV; w += 4)
        *reinterpret_cast<float4*>(ob + w) = make_float4(o[w], o[w+1], o[w+2], o[w+3]);
}

extern "C" void kernel_launch(void* const* d_in, const int* in_sizes, int n_in,
                              void* d_out, int out_size, void* d_ws, size_t ws_size,
                              hipStream_t stream) {
    const float* x = (const float*)d_in[0];
    const float* a = (const float*)d_in[1];
    const float* W = (const float*)d_in[2];
    const float* b = (const float*)d_in[3];

    float* out   = (float*)d_out;
    float* out_a = out + (size_t)NN * FF * TT * VV;

    const size_t wt_bytes = (size_t)FF * CC * sizeof(_Float16);  // 131072

    if (ws_size >= wt_bytes) {
        _Float16* Wt = (_Float16*)d_ws;
        wt_prep_kernel<<<dim3(CC), dim3(FF), 0, stream>>>(W, Wt);
        sgcn_mfma10_kernel<<<dim3(NN * (TT / TB)), dim3(512), 0, stream>>>(x, a, Wt, b, out, out_a);
    } else {
        sgcn_fused_kernel<<<dim3(NN * TT), dim3(256), 0, stream>>>(x, a, W, b, out, out_a);
    }
}